// Round 13
// baseline (361.764 us; speedup 1.0000x reference)
//
#include <hip/hip_runtime.h>
#include <math.h>

// ---------------------------------------------------------------------------
// AGNNet: GAT-like 3-layer GNN. N=100000 nodes, E=800000 edges, HID=64.
// R13 = R12 with all GEMM bodies K-chunked at 32 (LDS 33.8->17.2 KB,
// 4->8 blocks/CU) -- staging-only change, FMA order bit-identical
// (k ascending, bias-init acc). Gather/att/place/scans identical to R12.
// ---------------------------------------------------------------------------

#define HID 64
#define INC 128

// ---------------- Megakernel: in_gemm (bid%3==0) || degree count ----------
__global__ __launch_bounds__(256) void k_ingemm_deg(
    const float* __restrict__ x, const float* __restrict__ Win,
    const float* __restrict__ bin, const float* __restrict__ wp,
    const float* __restrict__ attw,
    float* __restrict__ h0, float* __restrict__ delta, float* __restrict__ hwp,
    float* __restrict__ ai, float* __restrict__ aj, int n,
    const int* __restrict__ dst, int* __restrict__ deg, int E)
{
    __shared__ float xs[64 * 36];     // 9.2 KB (one 32-wide K chunk of x)
    __shared__ float Ws[32 * 64];     // 8 KB  (one 32-row chunk of W_in)
    const int t = threadIdx.x;
    const int bid = blockIdx.x;

    if (bid % 3 != 0) {
        // ---- degree branch ----
        const int did = (bid / 3) * 2 + (bid % 3 - 1);
        const int e = did * 256 + t;
        if (e < E) atomicAdd(deg + dst[e], 1);
        return;
    }

    // ---- in_gemm branch: 64-node tile, K in 4x32 ascending chunks ----
    const int node0 = (bid / 3) * 64;
    const int cx = t & 15;
    const int ny = t >> 4;

    float acc[4][4];
    const float4 bv = *(const float4*)&bin[cx * 4];
    #pragma unroll
    for (int i = 0; i < 4; ++i) {
        acc[i][0] = bv.x; acc[i][1] = bv.y; acc[i][2] = bv.z; acc[i][3] = bv.w;
    }

    for (int ch = 0; ch < 4; ++ch) {
        if (ch) __syncthreads();
        // stage x chunk: 64 rows x 32 cols = 512 float4
        #pragma unroll
        for (int p = 0; p < 2; ++p) {
            int c = t + p * 256;
            int row = c >> 3;
            int col = (c & 7) * 4;
            float4 v = make_float4(0.f, 0.f, 0.f, 0.f);
            if (node0 + row < n)
                v = *(const float4*)&x[(size_t)(node0 + row) * INC + ch * 32 + col];
            *(float4*)&xs[row * 36 + col] = v;
        }
        // stage W chunk rows ch*32..+31 (2048 consecutive floats)
        #pragma unroll
        for (int p = 0; p < 2; ++p) {
            int c = t + p * 256;
            *(float4*)&Ws[c * 4] = *(const float4*)&Win[(size_t)ch * 32 * HID + c * 4];
        }
        __syncthreads();

        #pragma unroll
        for (int k4 = 0; k4 < 8; ++k4) {
            float4 xv[4];
            #pragma unroll
            for (int i = 0; i < 4; ++i)
                xv[i] = *(const float4*)&xs[(i * 16 + ny) * 36 + k4 * 4];
            #pragma unroll
            for (int kk = 0; kk < 4; ++kk) {
                float4 w = *(const float4*)&Ws[(k4 * 4 + kk) * HID + cx * 4];
                #pragma unroll
                for (int i = 0; i < 4; ++i) {
                    float xval = reinterpret_cast<const float*>(&xv[i])[kk];
                    acc[i][0] = fmaf(xval, w.x, acc[i][0]);
                    acc[i][1] = fmaf(xval, w.y, acc[i][1]);
                    acc[i][2] = fmaf(xval, w.z, acc[i][2]);
                    acc[i][3] = fmaf(xval, w.w, acc[i][3]);
                }
            }
        }
    }

    const float4 wpv = *(const float4*)&wp[cx * 4];
    const float4 wiv = *(const float4*)&attw[cx * 4];
    const float4 wjv = *(const float4*)&attw[HID + cx * 4];

    #pragma unroll
    for (int i = 0; i < 4; ++i) {
        const int node = node0 + i * 16 + ny;
        float h0v = fmaxf(acc[i][0], 0.f);
        float h1v = fmaxf(acc[i][1], 0.f);
        float h2v = fmaxf(acc[i][2], 0.f);
        float h3v = fmaxf(acc[i][3], 0.f);
        if (node < n) {
            float4 hv = make_float4(h0v, h1v, h2v, h3v);
            *(float4*)&h0[(size_t)node * HID + cx * 4] = hv;
        }
        float vd = h0v + h1v + h2v + h3v;
        float vw = h0v * wpv.x + h1v * wpv.y + h2v * wpv.z + h3v * wpv.w;
        float vi = h0v * wiv.x + h1v * wiv.y + h2v * wiv.z + h3v * wiv.w;
        float vj = h0v * wjv.x + h1v * wjv.y + h2v * wjv.z + h3v * wjv.w;
        #pragma unroll
        for (int m = 1; m < 16; m <<= 1) {
            vd += __shfl_xor(vd, m);
            vw += __shfl_xor(vw, m);
            vi += __shfl_xor(vi, m);
            vj += __shfl_xor(vj, m);
        }
        if (cx == 0 && node < n) {
            delta[node] = vd; hwp[node] = vw; ai[node] = vi; aj[node] = vj;
        }
    }
}

// ---------------- CSR scans (R12 exact) ----------------
__global__ __launch_bounds__(256) void k_scan1(
    const int* __restrict__ deg, int* __restrict__ rowptr,
    int* __restrict__ bsum, int n)
{
    __shared__ int sdata[256];
    const int t = threadIdx.x;
    const int i0 = blockIdx.x * 1024 + t * 4;
    int v[4];
    #pragma unroll
    for (int j = 0; j < 4; ++j) v[j] = (i0 + j < n) ? deg[i0 + j] : 0;
    int ts = v[0] + v[1] + v[2] + v[3];
    sdata[t] = ts;
    __syncthreads();
    for (int off = 1; off < 256; off <<= 1) {
        int add = (t >= off) ? sdata[t - off] : 0;
        __syncthreads();
        sdata[t] += add;
        __syncthreads();
    }
    int excl = sdata[t] - ts;
    int run = excl;
    #pragma unroll
    for (int j = 0; j < 4; ++j) {
        if (i0 + j < n) rowptr[i0 + j] = run;
        run += v[j];
    }
    if (t == 255) bsum[blockIdx.x] = sdata[255];
}

__global__ __launch_bounds__(128) void k_scan2(int* __restrict__ bsum, int B)
{
    __shared__ int sdata[128];
    const int t = threadIdx.x;
    int v = (t < B) ? bsum[t] : 0;
    sdata[t] = v;
    __syncthreads();
    for (int off = 1; off < 128; off <<= 1) {
        int add = (t >= off) ? sdata[t - off] : 0;
        __syncthreads();
        sdata[t] += add;
        __syncthreads();
    }
    if (t < B) bsum[t] = sdata[t] - v;
}

__global__ __launch_bounds__(256) void k_scan3(
    int* __restrict__ rowptr, int* __restrict__ cursor,
    const int* __restrict__ bsum, int n, int E)
{
    const int t = threadIdx.x;
    const int i0 = blockIdx.x * 1024 + t * 4;
    const int add = bsum[blockIdx.x];
    #pragma unroll
    for (int j = 0; j < 4; ++j) {
        int i = i0 + j;
        if (i < n) {
            int r = rowptr[i] + add;
            rowptr[i] = r;
            cursor[i] = r;
        }
    }
    if (blockIdx.x == 0 && t == 0) rowptr[n] = E;
}

// ---------------- Megakernel: place (bid%3!=0) || gemm64 layer-0 ----------
__global__ __launch_bounds__(256) void k_place_gemm(
    const int* __restrict__ src, const int* __restrict__ dst,
    int* __restrict__ cursor, int* __restrict__ csr_src, int E,
    const float* __restrict__ hin, const float* __restrict__ W,
    const float* __restrict__ b, float* __restrict__ hout, int n)
{
    __shared__ float xs[64 * 36];     // 9.2 KB
    __shared__ float Ws[32 * 64];     // 8 KB
    const int t = threadIdx.x;
    const int bid = blockIdx.x;

    if (bid % 3 != 0) {
        const int pid = (bid / 3) * 2 + (bid % 3 - 1);
        const int e = pid * 256 + t;
        if (e < E) {
            int slot = atomicAdd(cursor + dst[e], 1);
            csr_src[slot] = src[e];
        }
        return;
    }

    const int node0 = (bid / 3) * 64;
    const int cx = t & 15;
    const int ny = t >> 4;

    float acc[4][4];
    const float4 bv = *(const float4*)&b[cx * 4];
    #pragma unroll
    for (int i = 0; i < 4; ++i) {
        acc[i][0] = bv.x; acc[i][1] = bv.y; acc[i][2] = bv.z; acc[i][3] = bv.w;
    }

    for (int ch = 0; ch < 2; ++ch) {
        if (ch) __syncthreads();
        #pragma unroll
        for (int p = 0; p < 2; ++p) {
            int c = t + p * 256;
            int row = c >> 3;
            int col = (c & 7) * 4;
            float4 v = make_float4(0.f, 0.f, 0.f, 0.f);
            if (node0 + row < n)
                v = *(const float4*)&hin[(size_t)(node0 + row) * HID + ch * 32 + col];
            *(float4*)&xs[row * 36 + col] = v;
        }
        #pragma unroll
        for (int p = 0; p < 2; ++p) {
            int c = t + p * 256;
            *(float4*)&Ws[c * 4] = *(const float4*)&W[(size_t)ch * 32 * HID + c * 4];
        }
        __syncthreads();

        #pragma unroll
        for (int k4 = 0; k4 < 8; ++k4) {
            float4 xv[4];
            #pragma unroll
            for (int i = 0; i < 4; ++i)
                xv[i] = *(const float4*)&xs[(i * 16 + ny) * 36 + k4 * 4];
            #pragma unroll
            for (int kk = 0; kk < 4; ++kk) {
                float4 w = *(const float4*)&Ws[(k4 * 4 + kk) * HID + cx * 4];
                #pragma unroll
                for (int i = 0; i < 4; ++i) {
                    float xval = reinterpret_cast<const float*>(&xv[i])[kk];
                    acc[i][0] = fmaf(xval, w.x, acc[i][0]);
                    acc[i][1] = fmaf(xval, w.y, acc[i][1]);
                    acc[i][2] = fmaf(xval, w.z, acc[i][2]);
                    acc[i][3] = fmaf(xval, w.w, acc[i][3]);
                }
            }
        }
    }

    #pragma unroll
    for (int i = 0; i < 4; ++i) {
        const int node = node0 + i * 16 + ny;
        if (node < n) {
            float4 hv = make_float4(acc[i][0], acc[i][1], acc[i][2], acc[i][3]);
            *(float4*)&hout[(size_t)node * HID + cx * 4] = hv;
        }
    }
}

// ---------------- Attention prep (R12 exact) ----------------
__global__ __launch_bounds__(256) void k_neigh_pi(
    const int* __restrict__ rowptr, const int* __restrict__ csr_src,
    const float* __restrict__ delta, const float* __restrict__ hwp,
    float* __restrict__ pi, int n)
{
    int i = blockIdx.x * 256 + threadIdx.x;
    if (i >= n) return;
    int p0 = rowptr[i], p1 = rowptr[i + 1];
    float s = 0.f;
    for (int p = p0; p < p1; ++p) s += delta[csr_src[p]];
    float v = hwp[i] + s;
    pi[i] = 1.f / (1.f + expf(-v));
}

__global__ __launch_bounds__(256) void k_att(
    const int* __restrict__ rowptr, const int* __restrict__ csr_src,
    const float* __restrict__ ai, const float* __restrict__ aj,
    const float* __restrict__ pi, const float* __restrict__ attw,
    const float* __restrict__ attb,
    float* __restrict__ alpha_csr, int n)
{
    int i = blockIdx.x * 256 + threadIdx.x;
    if (i >= n) return;
    const float wpe = attw[2 * HID];
    const float ab  = attb[0];
    int p0 = rowptr[i], p1 = rowptr[i + 1];
    float aid = ai[i];
    float den = 0.f;
    for (int p = p0; p < p1; ++p) {
        int s = csr_src[p];
        float v = aid + aj[s] + pi[s] * wpe + ab;
        v = v > 0.f ? v : 0.2f * v;
        float ev = expf(v);
        alpha_csr[p] = ev;
        den += ev;
    }
    float inv = 1.f / (den + 1e-16f);
    for (int p = p0; p < p1; ++p) alpha_csr[p] *= inv;
}

// ---------------- GEMM 64x64, K chunked 2x32 ----------------
__global__ __launch_bounds__(256) void k_gemm64(
    const float* __restrict__ hin, const float* __restrict__ W,
    const float* __restrict__ b, float* __restrict__ hout, int n, int relu_in)
{
    __shared__ float xs[64 * 36];     // 9.2 KB
    __shared__ float Ws[32 * 64];     // 8 KB
    const int t = threadIdx.x;
    const int node0 = blockIdx.x * 64;
    const int cx = t & 15;
    const int ny = t >> 4;

    float acc[4][4];
    const float4 bv = *(const float4*)&b[cx * 4];
    #pragma unroll
    for (int i = 0; i < 4; ++i) {
        acc[i][0] = bv.x; acc[i][1] = bv.y; acc[i][2] = bv.z; acc[i][3] = bv.w;
    }

    for (int ch = 0; ch < 2; ++ch) {
        if (ch) __syncthreads();
        #pragma unroll
        for (int p = 0; p < 2; ++p) {
            int c = t + p * 256;
            int row = c >> 3;
            int col = (c & 7) * 4;
            float4 v = make_float4(0.f, 0.f, 0.f, 0.f);
            if (node0 + row < n)
                v = *(const float4*)&hin[(size_t)(node0 + row) * HID + ch * 32 + col];
            if (relu_in) {
                v.x = fmaxf(v.x, 0.f); v.y = fmaxf(v.y, 0.f);
                v.z = fmaxf(v.z, 0.f); v.w = fmaxf(v.w, 0.f);
            }
            *(float4*)&xs[row * 36 + col] = v;
        }
        #pragma unroll
        for (int p = 0; p < 2; ++p) {
            int c = t + p * 256;
            *(float4*)&Ws[c * 4] = *(const float4*)&W[(size_t)ch * 32 * HID + c * 4];
        }
        __syncthreads();

        #pragma unroll
        for (int k4 = 0; k4 < 8; ++k4) {
            float4 xv[4];
            #pragma unroll
            for (int i = 0; i < 4; ++i)
                xv[i] = *(const float4*)&xs[(i * 16 + ny) * 36 + k4 * 4];
            #pragma unroll
            for (int kk = 0; kk < 4; ++kk) {
                float4 w = *(const float4*)&Ws[(k4 * 4 + kk) * HID + cx * 4];
                #pragma unroll
                for (int i = 0; i < 4; ++i) {
                    float xval = reinterpret_cast<const float*>(&xv[i])[kk];
                    acc[i][0] = fmaf(xval, w.x, acc[i][0]);
                    acc[i][1] = fmaf(xval, w.y, acc[i][1]);
                    acc[i][2] = fmaf(xval, w.z, acc[i][2]);
                    acc[i][3] = fmaf(xval, w.w, acc[i][3]);
                }
            }
        }
    }

    #pragma unroll
    for (int i = 0; i < 4; ++i) {
        const int node = node0 + i * 16 + ny;
        if (node < n) {
            float4 hv = make_float4(acc[i][0], acc[i][1], acc[i][2], acc[i][3]);
            *(float4*)&hout[(size_t)node * HID + cx * 4] = hv;
        }
    }
}

// ---------------- Gather (R12 exact): out[d] = Sum alpha * hl[src] --------
__global__ __launch_bounds__(256) void k_gather(
    const int* __restrict__ rowptr, const int* __restrict__ csr_src,
    const float* __restrict__ alpha_csr, const float* __restrict__ hl,
    float* __restrict__ out, int n)
{
    const int wave = threadIdx.x >> 6;
    const int lane = threadIdx.x & 63;
    const int g    = lane >> 4;
    const int q    = lane & 15;
    const int node = blockIdx.x * 4 + wave;
    if (node >= n) return;

    const int p0 = rowptr[node], p1 = rowptr[node + 1];
    float4 acc = make_float4(0.f, 0.f, 0.f, 0.f);

    for (int base = p0; base < p1; base += 64) {
        int m = p1 - base; if (m > 64) m = 64;
        float a_l = 0.f; int s_l = 0;
        if (lane < m) { a_l = alpha_csr[base + lane]; s_l = csr_src[base + lane]; }
        for (int j = 0; j < m; j += 4) {
            const int e = j + g;
            float a = __shfl(a_l, e);
            int   s = __shfl(s_l, e);
            if (e < m) {
                float4 v = *(const float4*)&hl[(size_t)s * HID + q * 4];
                acc.x = fmaf(a, v.x, acc.x);
                acc.y = fmaf(a, v.y, acc.y);
                acc.z = fmaf(a, v.z, acc.z);
                acc.w = fmaf(a, v.w, acc.w);
            }
        }
    }
    #pragma unroll
    for (int m2 = 16; m2 <= 32; m2 <<= 1) {
        acc.x += __shfl_xor(acc.x, m2);
        acc.y += __shfl_xor(acc.y, m2);
        acc.z += __shfl_xor(acc.z, m2);
        acc.w += __shfl_xor(acc.w, m2);
    }
    if (g == 0)
        *(float4*)&out[(size_t)node * HID + q * 4] = acc;
}

// ---------------- Output GEMM 64x40, 128-node tile, K chunked 2x32 --------
__global__ __launch_bounds__(256) void k_out_gemm(
    const float* __restrict__ hin, const float* __restrict__ W,
    const float* __restrict__ b, float* __restrict__ out, int n)
{
    __shared__ float xs[128 * 36];    // 18.4 KB
    __shared__ float Ws[32 * 40];     // 5.1 KB
    const int t = threadIdx.x;
    const int node0 = blockIdx.x * 128;
    const int cx = t & 7;
    const int ny = t >> 3;

    float acc[4][5];
    #pragma unroll
    for (int j = 0; j < 5; ++j) {
        float bj = b[5 * cx + j];
        #pragma unroll
        for (int i = 0; i < 4; ++i) acc[i][j] = bj;
    }

    for (int ch = 0; ch < 2; ++ch) {
        if (ch) __syncthreads();
        // stage x chunk: 128 rows x 32 cols = 1024 float4 (relu at stage)
        #pragma unroll
        for (int p = 0; p < 4; ++p) {
            int c = t + p * 256;
            int row = c >> 3;
            int col = (c & 7) * 4;
            float4 v = make_float4(0.f, 0.f, 0.f, 0.f);
            if (node0 + row < n)
                v = *(const float4*)&hin[(size_t)(node0 + row) * HID + ch * 32 + col];
            v.x = fmaxf(v.x, 0.f); v.y = fmaxf(v.y, 0.f);
            v.z = fmaxf(v.z, 0.f); v.w = fmaxf(v.w, 0.f);
            *(float4*)&xs[row * 36 + col] = v;
        }
        // stage W chunk rows ch*32..+31: 32x40 = 320 float4
        #pragma unroll
        for (int p = 0; p < 2; ++p) {
            int c = t + p * 256;
            if (c < 320) *(float4*)&Ws[c * 4] = *(const float4*)&W[(size_t)ch * 32 * 40 + c * 4];
        }
        __syncthreads();

        #pragma unroll
        for (int k4 = 0; k4 < 8; ++k4) {
            float4 xv[4];
            #pragma unroll
            for (int i = 0; i < 4; ++i)
                xv[i] = *(const float4*)&xs[(i * 32 + ny) * 36 + k4 * 4];
            #pragma unroll
            for (int kk = 0; kk < 4; ++kk) {
                const int k = k4 * 4 + kk;
                float w[5];
                #pragma unroll
                for (int j = 0; j < 5; ++j) w[j] = Ws[k * 40 + 5 * cx + j];
                #pragma unroll
                for (int i = 0; i < 4; ++i) {
                    float xval = reinterpret_cast<const float*>(&xv[i])[kk];
                    #pragma unroll
                    for (int j = 0; j < 5; ++j)
                        acc[i][j] = fmaf(xval, w[j], acc[i][j]);
                }
            }
        }
    }

    #pragma unroll
    for (int i = 0; i < 4; ++i) {
        const int node = node0 + i * 32 + ny;
        if (node < n) {
            #pragma unroll
            for (int j = 0; j < 5; ++j)
                out[(size_t)node * 40 + 5 * cx + j] = acc[i][j];
        }
    }
}

extern "C" void kernel_launch(void* const* d_in, const int* in_sizes, int n_in,
                              void* d_out, int out_size, void* d_ws, size_t ws_size,
                              hipStream_t stream) {
    const float* x    = (const float*)d_in[0];
    const int*   ei   = (const int*)d_in[1];
    const float* Win  = (const float*)d_in[2];
    const float* bin  = (const float*)d_in[3];
    const float* wp   = (const float*)d_in[4];
    const float* attw = (const float*)d_in[5];
    const float* attb = (const float*)d_in[6];
    const float* Wout = (const float*)d_in[7];
    const float* bout = (const float*)d_in[8];
    const float* W0   = (const float*)d_in[9];
    const float* b0   = (const float*)d_in[10];
    const float* W1   = (const float*)d_in[11];
    const float* b1   = (const float*)d_in[12];
    const float* W2   = (const float*)d_in[13];
    const float* b2   = (const float*)d_in[14];

    const int N = in_sizes[0] / INC;
    const int E = in_sizes[1] / 2;
    const int* src = ei;
    const int* dst = ei + E;
    float* out = (float*)d_out;

    char* ws = (char*)d_ws;
    size_t off = 0;
    auto alloc = [&](size_t bytes) -> void* {
        void* p = ws + off;
        off = (off + bytes + 255) & ~(size_t)255;
        return p;
    };
    float* A       = (float*)alloc((size_t)N * HID * 4);
    float* Bf      = (float*)alloc((size_t)N * HID * 4);
    float* C       = (float*)alloc((size_t)N * HID * 4);
    float* delta   = (float*)alloc((size_t)N * 4);
    float* hwp     = (float*)alloc((size_t)N * 4);
    float* ai      = (float*)alloc((size_t)N * 4);
    float* aj      = (float*)alloc((size_t)N * 4);
    float* pi      = (float*)alloc((size_t)N * 4);
    int*   deg     = (int*)alloc((size_t)N * 4);
    int*   rowptr  = (int*)alloc((size_t)(N + 1) * 4);
    int*   cursor  = (int*)alloc((size_t)N * 4);
    int*   bsum    = (int*)alloc(256 * 4);
    int*   csr_src = (int*)alloc((size_t)E * 4);
    float* alpha   = (float*)alloc((size_t)E * 4);

    const int tileBlocks64  = (N + 63) / 64;          // 1563
    const int tileBlocks128 = (N + 127) / 128;
    const int nodeBlocks256 = (N + 255) / 256;
    const int nodeBlocksW   = (N + 3) / 4;
    const int scanBlocks    = (N + 1023) / 1024;      // 98

    // 1 gemm block : 2 edge blocks; 2*1563=3126 >= ceil(E/256)=3125 (guarded)
    const int fusedBlocks = 3 * tileBlocks64;

    hipMemsetAsync(deg, 0, (size_t)N * 4, stream);

    // ---- in_gemm || degree count ----
    k_ingemm_deg<<<fusedBlocks, 256, 0, stream>>>(
        x, Win, bin, wp, attw, A, delta, hwp, ai, aj, N, dst, deg, E);

    // ---- rowptr scans ----
    k_scan1<<<scanBlocks, 256, 0, stream>>>(deg, rowptr, bsum, N);
    k_scan2<<<1, 128, 0, stream>>>(bsum, scanBlocks);
    k_scan3<<<scanBlocks, 256, 0, stream>>>(rowptr, cursor, bsum, N, E);

    // ---- place || gemm64 layer-0 (Bf = h0 @ W0 + b0) ----
    k_place_gemm<<<fusedBlocks, 256, 0, stream>>>(
        src, dst, cursor, csr_src, E, A, W0, b0, Bf, N);

    // ---- attention ----
    k_neigh_pi<<<nodeBlocks256, 256, 0, stream>>>(rowptr, csr_src, delta, hwp, pi, N);
    k_att<<<nodeBlocks256, 256, 0, stream>>>(rowptr, csr_src, ai, aj, pi,
                                             attw, attb, alpha, N);

    // ---- layers ----
    k_gather<<<nodeBlocksW, 256, 0, stream>>>(rowptr, csr_src, alpha, Bf, C, N);

    k_gemm64<<<tileBlocks64, 256, 0, stream>>>(C, W1, b1, A, N, 1);
    k_gather<<<nodeBlocksW, 256, 0, stream>>>(rowptr, csr_src, alpha, A, Bf, N);

    k_gemm64<<<tileBlocks64, 256, 0, stream>>>(Bf, W2, b2, C, N, 1);
    k_gather<<<nodeBlocksW, 256, 0, stream>>>(rowptr, csr_src, alpha, C, A, N);

    k_out_gemm<<<tileBlocks128, 256, 0, stream>>>(A, Wout, bout, out, N);
}

// Round 14
// 296.005 us; speedup vs baseline: 1.2222x; 1.2222x over previous
//
#include <hip/hip_runtime.h>
#include <math.h>

// ---------------------------------------------------------------------------
// AGNNet: GAT-like 3-layer GNN. N=100000 nodes, E=800000 edges, HID=64.
// R14 = R12 exact (R13's K-32 chunking reverted: it blew VGPR 52->252,
// occupancy 9%) + order-preserving gather MLP: preload 2-4 edges before
// their FMAs with ONE accumulator chain -> per-lane FMA sequence identical
// to R12 (bit-exact), memory-level parallelism 2-4x.
// ---------------------------------------------------------------------------

#define HID 64
#define INC 128

// ---------------- Megakernel: in_gemm (bid%3==0) || degree count ----------
__global__ __launch_bounds__(256) void k_ingemm_deg(
    const float* __restrict__ x, const float* __restrict__ Win,
    const float* __restrict__ bin, const float* __restrict__ wp,
    const float* __restrict__ attw,
    float* __restrict__ h0, float* __restrict__ delta, float* __restrict__ hwp,
    float* __restrict__ ai, float* __restrict__ aj, int n,
    const int* __restrict__ dst, int* __restrict__ deg, int E)
{
    __shared__ float xs[64 * 68];     // 17.4 KB
    __shared__ float Ws[64 * 64];     // 16 KB (one K-chunk)
    const int t = threadIdx.x;
    const int bid = blockIdx.x;

    if (bid % 3 != 0) {
        // ---- degree branch ----
        const int did = (bid / 3) * 2 + (bid % 3 - 1);
        const int e = did * 256 + t;
        if (e < E) atomicAdd(deg + dst[e], 1);
        return;
    }

    // ---- in_gemm branch: 64-node tile, K in 2x64 ascending chunks ----
    const int node0 = (bid / 3) * 64;
    const int cx = t & 15;
    const int ny = t >> 4;

    float acc[4][4];
    const float4 bv = *(const float4*)&bin[cx * 4];
    #pragma unroll
    for (int i = 0; i < 4; ++i) {
        acc[i][0] = bv.x; acc[i][1] = bv.y; acc[i][2] = bv.z; acc[i][3] = bv.w;
    }

    #pragma unroll
    for (int ch = 0; ch < 2; ++ch) {
        if (ch) __syncthreads();
        #pragma unroll
        for (int p = 0; p < 4; ++p) {
            int c = t + p * 256;
            int row = c >> 4;
            int col = (c & 15) * 4;
            float4 v = make_float4(0.f, 0.f, 0.f, 0.f);
            if (node0 + row < n)
                v = *(const float4*)&x[(size_t)(node0 + row) * INC + ch * 64 + col];
            *(float4*)&xs[row * 68 + col] = v;
        }
        #pragma unroll
        for (int p = 0; p < 4; ++p) {
            int c = t + p * 256;
            *(float4*)&Ws[c * 4] = *(const float4*)&Win[(size_t)ch * 64 * HID + c * 4];
        }
        __syncthreads();

        #pragma unroll 4
        for (int k4 = 0; k4 < 16; ++k4) {
            float4 xv[4];
            #pragma unroll
            for (int i = 0; i < 4; ++i)
                xv[i] = *(const float4*)&xs[(i * 16 + ny) * 68 + k4 * 4];
            #pragma unroll
            for (int kk = 0; kk < 4; ++kk) {
                float4 w = *(const float4*)&Ws[(k4 * 4 + kk) * HID + cx * 4];
                #pragma unroll
                for (int i = 0; i < 4; ++i) {
                    float xval = reinterpret_cast<const float*>(&xv[i])[kk];
                    acc[i][0] = fmaf(xval, w.x, acc[i][0]);
                    acc[i][1] = fmaf(xval, w.y, acc[i][1]);
                    acc[i][2] = fmaf(xval, w.z, acc[i][2]);
                    acc[i][3] = fmaf(xval, w.w, acc[i][3]);
                }
            }
        }
    }

    const float4 wpv = *(const float4*)&wp[cx * 4];
    const float4 wiv = *(const float4*)&attw[cx * 4];
    const float4 wjv = *(const float4*)&attw[HID + cx * 4];

    #pragma unroll
    for (int i = 0; i < 4; ++i) {
        const int node = node0 + i * 16 + ny;
        float h0v = fmaxf(acc[i][0], 0.f);
        float h1v = fmaxf(acc[i][1], 0.f);
        float h2v = fmaxf(acc[i][2], 0.f);
        float h3v = fmaxf(acc[i][3], 0.f);
        if (node < n) {
            float4 hv = make_float4(h0v, h1v, h2v, h3v);
            *(float4*)&h0[(size_t)node * HID + cx * 4] = hv;
        }
        float vd = h0v + h1v + h2v + h3v;
        float vw = h0v * wpv.x + h1v * wpv.y + h2v * wpv.z + h3v * wpv.w;
        float vi = h0v * wiv.x + h1v * wiv.y + h2v * wiv.z + h3v * wiv.w;
        float vj = h0v * wjv.x + h1v * wjv.y + h2v * wjv.z + h3v * wjv.w;
        #pragma unroll
        for (int m = 1; m < 16; m <<= 1) {
            vd += __shfl_xor(vd, m);
            vw += __shfl_xor(vw, m);
            vi += __shfl_xor(vi, m);
            vj += __shfl_xor(vj, m);
        }
        if (cx == 0 && node < n) {
            delta[node] = vd; hwp[node] = vw; ai[node] = vi; aj[node] = vj;
        }
    }
}

// ---------------- CSR scans (R12 exact) ----------------
__global__ __launch_bounds__(256) void k_scan1(
    const int* __restrict__ deg, int* __restrict__ rowptr,
    int* __restrict__ bsum, int n)
{
    __shared__ int sdata[256];
    const int t = threadIdx.x;
    const int i0 = blockIdx.x * 1024 + t * 4;
    int v[4];
    #pragma unroll
    for (int j = 0; j < 4; ++j) v[j] = (i0 + j < n) ? deg[i0 + j] : 0;
    int ts = v[0] + v[1] + v[2] + v[3];
    sdata[t] = ts;
    __syncthreads();
    for (int off = 1; off < 256; off <<= 1) {
        int add = (t >= off) ? sdata[t - off] : 0;
        __syncthreads();
        sdata[t] += add;
        __syncthreads();
    }
    int excl = sdata[t] - ts;
    int run = excl;
    #pragma unroll
    for (int j = 0; j < 4; ++j) {
        if (i0 + j < n) rowptr[i0 + j] = run;
        run += v[j];
    }
    if (t == 255) bsum[blockIdx.x] = sdata[255];
}

__global__ __launch_bounds__(128) void k_scan2(int* __restrict__ bsum, int B)
{
    __shared__ int sdata[128];
    const int t = threadIdx.x;
    int v = (t < B) ? bsum[t] : 0;
    sdata[t] = v;
    __syncthreads();
    for (int off = 1; off < 128; off <<= 1) {
        int add = (t >= off) ? sdata[t - off] : 0;
        __syncthreads();
        sdata[t] += add;
        __syncthreads();
    }
    if (t < B) bsum[t] = sdata[t] - v;
}

__global__ __launch_bounds__(256) void k_scan3(
    int* __restrict__ rowptr, int* __restrict__ cursor,
    const int* __restrict__ bsum, int n, int E)
{
    const int t = threadIdx.x;
    const int i0 = blockIdx.x * 1024 + t * 4;
    const int add = bsum[blockIdx.x];
    #pragma unroll
    for (int j = 0; j < 4; ++j) {
        int i = i0 + j;
        if (i < n) {
            int r = rowptr[i] + add;
            rowptr[i] = r;
            cursor[i] = r;
        }
    }
    if (blockIdx.x == 0 && t == 0) rowptr[n] = E;
}

// ---------------- Megakernel: place (bid%3!=0) || gemm64 layer-0 ----------
__global__ __launch_bounds__(256) void k_place_gemm(
    const int* __restrict__ src, const int* __restrict__ dst,
    int* __restrict__ cursor, int* __restrict__ csr_src, int E,
    const float* __restrict__ hin, const float* __restrict__ W,
    const float* __restrict__ b, float* __restrict__ hout, int n)
{
    __shared__ float xs[64 * 68];
    __shared__ float Ws[HID * HID];
    const int t = threadIdx.x;
    const int bid = blockIdx.x;

    if (bid % 3 != 0) {
        const int pid = (bid / 3) * 2 + (bid % 3 - 1);
        const int e = pid * 256 + t;
        if (e < E) {
            int slot = atomicAdd(cursor + dst[e], 1);
            csr_src[slot] = src[e];
        }
        return;
    }

    const int node0 = (bid / 3) * 64;

    #pragma unroll
    for (int p = 0; p < 4; ++p) {
        int c = t + p * 256;
        *(float4*)&Ws[c * 4] = *(const float4*)&W[c * 4];
    }
    #pragma unroll
    for (int p = 0; p < 4; ++p) {
        int c = t + p * 256;
        int row = c >> 4;
        int col = (c & 15) * 4;
        float4 v = make_float4(0.f, 0.f, 0.f, 0.f);
        if (node0 + row < n) v = *(const float4*)&hin[(size_t)(node0 + row) * HID + col];
        *(float4*)&xs[row * 68 + col] = v;
    }
    __syncthreads();

    const int cx = t & 15;
    const int ny = t >> 4;
    float acc[4][4];
    const float4 bv = *(const float4*)&b[cx * 4];
    #pragma unroll
    for (int i = 0; i < 4; ++i) {
        acc[i][0] = bv.x; acc[i][1] = bv.y; acc[i][2] = bv.z; acc[i][3] = bv.w;
    }

    #pragma unroll 4
    for (int k4 = 0; k4 < 16; ++k4) {
        float4 xv[4];
        #pragma unroll
        for (int i = 0; i < 4; ++i)
            xv[i] = *(const float4*)&xs[(i * 16 + ny) * 68 + k4 * 4];
        #pragma unroll
        for (int kk = 0; kk < 4; ++kk) {
            float4 w = *(const float4*)&Ws[(k4 * 4 + kk) * HID + cx * 4];
            #pragma unroll
            for (int i = 0; i < 4; ++i) {
                float xval = reinterpret_cast<const float*>(&xv[i])[kk];
                acc[i][0] = fmaf(xval, w.x, acc[i][0]);
                acc[i][1] = fmaf(xval, w.y, acc[i][1]);
                acc[i][2] = fmaf(xval, w.z, acc[i][2]);
                acc[i][3] = fmaf(xval, w.w, acc[i][3]);
            }
        }
    }

    #pragma unroll
    for (int i = 0; i < 4; ++i) {
        const int node = node0 + i * 16 + ny;
        if (node < n) {
            float4 hv = make_float4(acc[i][0], acc[i][1], acc[i][2], acc[i][3]);
            *(float4*)&hout[(size_t)node * HID + cx * 4] = hv;
        }
    }
}

// ---------------- Attention prep (R12 exact) ----------------
__global__ __launch_bounds__(256) void k_neigh_pi(
    const int* __restrict__ rowptr, const int* __restrict__ csr_src,
    const float* __restrict__ delta, const float* __restrict__ hwp,
    float* __restrict__ pi, int n)
{
    int i = blockIdx.x * 256 + threadIdx.x;
    if (i >= n) return;
    int p0 = rowptr[i], p1 = rowptr[i + 1];
    float s = 0.f;
    for (int p = p0; p < p1; ++p) s += delta[csr_src[p]];
    float v = hwp[i] + s;
    pi[i] = 1.f / (1.f + expf(-v));
}

__global__ __launch_bounds__(256) void k_att(
    const int* __restrict__ rowptr, const int* __restrict__ csr_src,
    const float* __restrict__ ai, const float* __restrict__ aj,
    const float* __restrict__ pi, const float* __restrict__ attw,
    const float* __restrict__ attb,
    float* __restrict__ alpha_csr, int n)
{
    int i = blockIdx.x * 256 + threadIdx.x;
    if (i >= n) return;
    const float wpe = attw[2 * HID];
    const float ab  = attb[0];
    int p0 = rowptr[i], p1 = rowptr[i + 1];
    float aid = ai[i];
    float den = 0.f;
    for (int p = p0; p < p1; ++p) {
        int s = csr_src[p];
        float v = aid + aj[s] + pi[s] * wpe + ab;
        v = v > 0.f ? v : 0.2f * v;
        float ev = expf(v);
        alpha_csr[p] = ev;
        den += ev;
    }
    float inv = 1.f / (den + 1e-16f);
    for (int p = p0; p < p1; ++p) alpha_csr[p] *= inv;
}

// ---------------- GEMM 64x64 (R12 exact, staged) ----------------
__global__ __launch_bounds__(256) void k_gemm64(
    const float* __restrict__ hin, const float* __restrict__ W,
    const float* __restrict__ b, float* __restrict__ hout, int n, int relu_in)
{
    __shared__ float xs[64 * 68];
    __shared__ float Ws[HID * HID];
    const int t = threadIdx.x;
    const int node0 = blockIdx.x * 64;

    #pragma unroll
    for (int p = 0; p < 4; ++p) {
        int c = t + p * 256;
        *(float4*)&Ws[c * 4] = *(const float4*)&W[c * 4];
    }
    #pragma unroll
    for (int p = 0; p < 4; ++p) {
        int c = t + p * 256;
        int row = c >> 4;
        int col = (c & 15) * 4;
        float4 v = make_float4(0.f, 0.f, 0.f, 0.f);
        if (node0 + row < n) v = *(const float4*)&hin[(size_t)(node0 + row) * HID + col];
        if (relu_in) {
            v.x = fmaxf(v.x, 0.f); v.y = fmaxf(v.y, 0.f);
            v.z = fmaxf(v.z, 0.f); v.w = fmaxf(v.w, 0.f);
        }
        *(float4*)&xs[row * 68 + col] = v;
    }
    __syncthreads();

    const int cx = t & 15;
    const int ny = t >> 4;
    float acc[4][4];
    const float4 bv = *(const float4*)&b[cx * 4];
    #pragma unroll
    for (int i = 0; i < 4; ++i) {
        acc[i][0] = bv.x; acc[i][1] = bv.y; acc[i][2] = bv.z; acc[i][3] = bv.w;
    }

    #pragma unroll 4
    for (int k4 = 0; k4 < 16; ++k4) {
        float4 xv[4];
        #pragma unroll
        for (int i = 0; i < 4; ++i)
            xv[i] = *(const float4*)&xs[(i * 16 + ny) * 68 + k4 * 4];
        #pragma unroll
        for (int kk = 0; kk < 4; ++kk) {
            float4 w = *(const float4*)&Ws[(k4 * 4 + kk) * HID + cx * 4];
            #pragma unroll
            for (int i = 0; i < 4; ++i) {
                float xval = reinterpret_cast<const float*>(&xv[i])[kk];
                acc[i][0] = fmaf(xval, w.x, acc[i][0]);
                acc[i][1] = fmaf(xval, w.y, acc[i][1]);
                acc[i][2] = fmaf(xval, w.z, acc[i][2]);
                acc[i][3] = fmaf(xval, w.w, acc[i][3]);
            }
        }
    }

    #pragma unroll
    for (int i = 0; i < 4; ++i) {
        const int node = node0 + i * 16 + ny;
        if (node < n) {
            float4 hv = make_float4(acc[i][0], acc[i][1], acc[i][2], acc[i][3]);
            *(float4*)&hout[(size_t)node * HID + cx * 4] = hv;
        }
    }
}

// ---------------- Gather: out[d] = Sum alpha * hl[src] --------------------
// 4 edge-groups x 16 lanes x float4; ONE accumulator chain per lane with
// 2-4 edge preloading: per-lane FMA order (j+g ascending, stride 4) is
// IDENTICAL to R12 -> bit-exact; loads overlap 2-4x.
__global__ __launch_bounds__(256) void k_gather(
    const int* __restrict__ rowptr, const int* __restrict__ csr_src,
    const float* __restrict__ alpha_csr, const float* __restrict__ hl,
    float* __restrict__ out, int n)
{
    const int wave = threadIdx.x >> 6;
    const int lane = threadIdx.x & 63;
    const int g    = lane >> 4;
    const int q    = lane & 15;
    const int node = blockIdx.x * 4 + wave;
    if (node >= n) return;

    const int p0 = rowptr[node], p1 = rowptr[node + 1];
    float4 acc = make_float4(0.f, 0.f, 0.f, 0.f);

    for (int base = p0; base < p1; base += 64) {
        int m = p1 - base; if (m > 64) m = 64;
        float a_l = 0.f; int s_l = 0;
        if (lane < m) { a_l = alpha_csr[base + lane]; s_l = csr_src[base + lane]; }
        int j = 0;
        for (; j + 16 <= m; j += 16) {       // 4 edges in flight per group
            float a0 = __shfl(a_l, j + g);      int s0 = __shfl(s_l, j + g);
            float a1 = __shfl(a_l, j + 4 + g);  int s1 = __shfl(s_l, j + 4 + g);
            float a2 = __shfl(a_l, j + 8 + g);  int s2 = __shfl(s_l, j + 8 + g);
            float a3 = __shfl(a_l, j + 12 + g); int s3 = __shfl(s_l, j + 12 + g);
            float4 v0 = *(const float4*)&hl[(size_t)s0 * HID + q * 4];
            float4 v1 = *(const float4*)&hl[(size_t)s1 * HID + q * 4];
            float4 v2 = *(const float4*)&hl[(size_t)s2 * HID + q * 4];
            float4 v3 = *(const float4*)&hl[(size_t)s3 * HID + q * 4];
            acc.x = fmaf(a0, v0.x, acc.x); acc.y = fmaf(a0, v0.y, acc.y);
            acc.z = fmaf(a0, v0.z, acc.z); acc.w = fmaf(a0, v0.w, acc.w);
            acc.x = fmaf(a1, v1.x, acc.x); acc.y = fmaf(a1, v1.y, acc.y);
            acc.z = fmaf(a1, v1.z, acc.z); acc.w = fmaf(a1, v1.w, acc.w);
            acc.x = fmaf(a2, v2.x, acc.x); acc.y = fmaf(a2, v2.y, acc.y);
            acc.z = fmaf(a2, v2.z, acc.z); acc.w = fmaf(a2, v2.w, acc.w);
            acc.x = fmaf(a3, v3.x, acc.x); acc.y = fmaf(a3, v3.y, acc.y);
            acc.z = fmaf(a3, v3.z, acc.z); acc.w = fmaf(a3, v3.w, acc.w);
        }
        for (; j + 8 <= m; j += 8) {         // 2 edges in flight per group
            float a0 = __shfl(a_l, j + g);     int s0 = __shfl(s_l, j + g);
            float a1 = __shfl(a_l, j + 4 + g); int s1 = __shfl(s_l, j + 4 + g);
            float4 v0 = *(const float4*)&hl[(size_t)s0 * HID + q * 4];
            float4 v1 = *(const float4*)&hl[(size_t)s1 * HID + q * 4];
            acc.x = fmaf(a0, v0.x, acc.x); acc.y = fmaf(a0, v0.y, acc.y);
            acc.z = fmaf(a0, v0.z, acc.z); acc.w = fmaf(a0, v0.w, acc.w);
            acc.x = fmaf(a1, v1.x, acc.x); acc.y = fmaf(a1, v1.y, acc.y);
            acc.z = fmaf(a1, v1.z, acc.z); acc.w = fmaf(a1, v1.w, acc.w);
        }
        for (; j < m; j += 4) {              // guarded tail
            const int e = j + g;
            float a = __shfl(a_l, e);
            int   s = __shfl(s_l, e);
            if (e < m) {
                float4 v = *(const float4*)&hl[(size_t)s * HID + q * 4];
                acc.x = fmaf(a, v.x, acc.x);
                acc.y = fmaf(a, v.y, acc.y);
                acc.z = fmaf(a, v.z, acc.z);
                acc.w = fmaf(a, v.w, acc.w);
            }
        }
    }
    #pragma unroll
    for (int m2 = 16; m2 <= 32; m2 <<= 1) {
        acc.x += __shfl_xor(acc.x, m2);
        acc.y += __shfl_xor(acc.y, m2);
        acc.z += __shfl_xor(acc.z, m2);
        acc.w += __shfl_xor(acc.w, m2);
    }
    if (g == 0)
        *(float4*)&out[(size_t)node * HID + q * 4] = acc;
}

// ---------------- Output GEMM 64x40 (R12 exact, staged) ----------------
__global__ __launch_bounds__(256) void k_out_gemm(
    const float* __restrict__ hin, const float* __restrict__ W,
    const float* __restrict__ b, float* __restrict__ out, int n)
{
    __shared__ float xs[128 * 68];
    __shared__ float Ws[HID * 40];
    const int t = threadIdx.x;
    const int node0 = blockIdx.x * 128;

    #pragma unroll
    for (int p = 0; p < 3; ++p) {
        int c = t + p * 256;
        if (c < 640) *(float4*)&Ws[c * 4] = *(const float4*)&W[c * 4];
    }
    #pragma unroll
    for (int p = 0; p < 8; ++p) {
        int c = t + p * 256;
        int row = c >> 4;
        int col = (c & 15) * 4;
        float4 v = make_float4(0.f, 0.f, 0.f, 0.f);
        if (node0 + row < n) v = *(const float4*)&hin[(size_t)(node0 + row) * HID + col];
        v.x = fmaxf(v.x, 0.f); v.y = fmaxf(v.y, 0.f);
        v.z = fmaxf(v.z, 0.f); v.w = fmaxf(v.w, 0.f);
        *(float4*)&xs[row * 68 + col] = v;
    }
    __syncthreads();

    const int cx = t & 7;
    const int ny = t >> 3;
    float acc[4][5];
    #pragma unroll
    for (int j = 0; j < 5; ++j) {
        float bj = b[5 * cx + j];
        #pragma unroll
        for (int i = 0; i < 4; ++i) acc[i][j] = bj;
    }

    #pragma unroll 4
    for (int k4 = 0; k4 < 16; ++k4) {
        float4 xv[4];
        #pragma unroll
        for (int i = 0; i < 4; ++i)
            xv[i] = *(const float4*)&xs[(i * 32 + ny) * 68 + k4 * 4];
        #pragma unroll
        for (int kk = 0; kk < 4; ++kk) {
            int k = k4 * 4 + kk;
            float w[5];
            #pragma unroll
            for (int j = 0; j < 5; ++j) w[j] = Ws[k * 40 + 5 * cx + j];
            #pragma unroll
            for (int i = 0; i < 4; ++i) {
                float xval = reinterpret_cast<const float*>(&xv[i])[kk];
                #pragma unroll
                for (int j = 0; j < 5; ++j)
                    acc[i][j] = fmaf(xval, w[j], acc[i][j]);
            }
        }
    }

    #pragma unroll
    for (int i = 0; i < 4; ++i) {
        const int node = node0 + i * 32 + ny;
        if (node < n) {
            #pragma unroll
            for (int j = 0; j < 5; ++j)
                out[(size_t)node * 40 + 5 * cx + j] = acc[i][j];
        }
    }
}

extern "C" void kernel_launch(void* const* d_in, const int* in_sizes, int n_in,
                              void* d_out, int out_size, void* d_ws, size_t ws_size,
                              hipStream_t stream) {
    const float* x    = (const float*)d_in[0];
    const int*   ei   = (const int*)d_in[1];
    const float* Win  = (const float*)d_in[2];
    const float* bin  = (const float*)d_in[3];
    const float* wp   = (const float*)d_in[4];
    const float* attw = (const float*)d_in[5];
    const float* attb = (const float*)d_in[6];
    const float* Wout = (const float*)d_in[7];
    const float* bout = (const float*)d_in[8];
    const float* W0   = (const float*)d_in[9];
    const float* b0   = (const float*)d_in[10];
    const float* W1   = (const float*)d_in[11];
    const float* b1   = (const float*)d_in[12];
    const float* W2   = (const float*)d_in[13];
    const float* b2   = (const float*)d_in[14];

    const int N = in_sizes[0] / INC;
    const int E = in_sizes[1] / 2;
    const int* src = ei;
    const int* dst = ei + E;
    float* out = (float*)d_out;

    char* ws = (char*)d_ws;
    size_t off = 0;
    auto alloc = [&](size_t bytes) -> void* {
        void* p = ws + off;
        off = (off + bytes + 255) & ~(size_t)255;
        return p;
    };
    float* A       = (float*)alloc((size_t)N * HID * 4);
    float* Bf      = (float*)alloc((size_t)N * HID * 4);
    float* C       = (float*)alloc((size_t)N * HID * 4);
    float* delta   = (float*)alloc((size_t)N * 4);
    float* hwp     = (float*)alloc((size_t)N * 4);
    float* ai      = (float*)alloc((size_t)N * 4);
    float* aj      = (float*)alloc((size_t)N * 4);
    float* pi      = (float*)alloc((size_t)N * 4);
    int*   deg     = (int*)alloc((size_t)N * 4);
    int*   rowptr  = (int*)alloc((size_t)(N + 1) * 4);
    int*   cursor  = (int*)alloc((size_t)N * 4);
    int*   bsum    = (int*)alloc(256 * 4);
    int*   csr_src = (int*)alloc((size_t)E * 4);
    float* alpha   = (float*)alloc((size_t)E * 4);

    const int tileBlocks64  = (N + 63) / 64;          // 1563
    const int tileBlocks128 = (N + 127) / 128;
    const int nodeBlocks256 = (N + 255) / 256;
    const int nodeBlocksW   = (N + 3) / 4;
    const int scanBlocks    = (N + 1023) / 1024;      // 98

    // 1 gemm block : 2 edge blocks; 2*1563=3126 >= ceil(E/256)=3125 (guarded)
    const int fusedBlocks = 3 * tileBlocks64;

    hipMemsetAsync(deg, 0, (size_t)N * 4, stream);

    // ---- in_gemm || degree count ----
    k_ingemm_deg<<<fusedBlocks, 256, 0, stream>>>(
        x, Win, bin, wp, attw, A, delta, hwp, ai, aj, N, dst, deg, E);

    // ---- rowptr scans ----
    k_scan1<<<scanBlocks, 256, 0, stream>>>(deg, rowptr, bsum, N);
    k_scan2<<<1, 128, 0, stream>>>(bsum, scanBlocks);
    k_scan3<<<scanBlocks, 256, 0, stream>>>(rowptr, cursor, bsum, N, E);

    // ---- place || gemm64 layer-0 (Bf = h0 @ W0 + b0) ----
    k_place_gemm<<<fusedBlocks, 256, 0, stream>>>(
        src, dst, cursor, csr_src, E, A, W0, b0, Bf, N);

    // ---- attention ----
    k_neigh_pi<<<nodeBlocks256, 256, 0, stream>>>(rowptr, csr_src, delta, hwp, pi, N);
    k_att<<<nodeBlocks256, 256, 0, stream>>>(rowptr, csr_src, ai, aj, pi,
                                             attw, attb, alpha, N);

    // ---- layers ----
    k_gather<<<nodeBlocksW, 256, 0, stream>>>(rowptr, csr_src, alpha, Bf, C, N);

    k_gemm64<<<tileBlocks64, 256, 0, stream>>>(C, W1, b1, A, N, 1);
    k_gather<<<nodeBlocksW, 256, 0, stream>>>(rowptr, csr_src, alpha, A, Bf, N);

    k_gemm64<<<tileBlocks64, 256, 0, stream>>>(Bf, W2, b2, C, N, 1);
    k_gather<<<nodeBlocksW, 256, 0, stream>>>(rowptr, csr_src, alpha, C, A, N);

    k_out_gemm<<<tileBlocks128, 256, 0, stream>>>(A, Wout, bout, out, N);
}

// Round 15
// 291.112 us; speedup vs baseline: 1.2427x; 1.0168x over previous
//
#include <hip/hip_runtime.h>
#include <math.h>

// ---------------------------------------------------------------------------
// AGNNet: GAT-like 3-layer GNN. N=100000 nodes, E=800000 edges, HID=64.
// R15 = R14 exact + k_att folded into gather #0 (template FUSE_ATT):
// the gather wave computes per-edge exp(lrelu(.)) in-lane, tree-reduces the
// denominator (6 shfl_xor), normalizes, stores alpha for gathers 1/2, then
// gathers. Removes the serial k_att dispatch; att work hides under gather0's
// row-fetch latency. All other kernels byte-identical to R14.
// ---------------------------------------------------------------------------

#define HID 64
#define INC 128

// ---------------- Megakernel: in_gemm (bid%3==0) || degree count ----------
__global__ __launch_bounds__(256) void k_ingemm_deg(
    const float* __restrict__ x, const float* __restrict__ Win,
    const float* __restrict__ bin, const float* __restrict__ wp,
    const float* __restrict__ attw,
    float* __restrict__ h0, float* __restrict__ delta, float* __restrict__ hwp,
    float* __restrict__ ai, float* __restrict__ aj, int n,
    const int* __restrict__ dst, int* __restrict__ deg, int E)
{
    __shared__ float xs[64 * 68];     // 17.4 KB
    __shared__ float Ws[64 * 64];     // 16 KB (one K-chunk)
    const int t = threadIdx.x;
    const int bid = blockIdx.x;

    if (bid % 3 != 0) {
        // ---- degree branch ----
        const int did = (bid / 3) * 2 + (bid % 3 - 1);
        const int e = did * 256 + t;
        if (e < E) atomicAdd(deg + dst[e], 1);
        return;
    }

    // ---- in_gemm branch: 64-node tile, K in 2x64 ascending chunks ----
    const int node0 = (bid / 3) * 64;
    const int cx = t & 15;
    const int ny = t >> 4;

    float acc[4][4];
    const float4 bv = *(const float4*)&bin[cx * 4];
    #pragma unroll
    for (int i = 0; i < 4; ++i) {
        acc[i][0] = bv.x; acc[i][1] = bv.y; acc[i][2] = bv.z; acc[i][3] = bv.w;
    }

    #pragma unroll
    for (int ch = 0; ch < 2; ++ch) {
        if (ch) __syncthreads();
        #pragma unroll
        for (int p = 0; p < 4; ++p) {
            int c = t + p * 256;
            int row = c >> 4;
            int col = (c & 15) * 4;
            float4 v = make_float4(0.f, 0.f, 0.f, 0.f);
            if (node0 + row < n)
                v = *(const float4*)&x[(size_t)(node0 + row) * INC + ch * 64 + col];
            *(float4*)&xs[row * 68 + col] = v;
        }
        #pragma unroll
        for (int p = 0; p < 4; ++p) {
            int c = t + p * 256;
            *(float4*)&Ws[c * 4] = *(const float4*)&Win[(size_t)ch * 64 * HID + c * 4];
        }
        __syncthreads();

        #pragma unroll 4
        for (int k4 = 0; k4 < 16; ++k4) {
            float4 xv[4];
            #pragma unroll
            for (int i = 0; i < 4; ++i)
                xv[i] = *(const float4*)&xs[(i * 16 + ny) * 68 + k4 * 4];
            #pragma unroll
            for (int kk = 0; kk < 4; ++kk) {
                float4 w = *(const float4*)&Ws[(k4 * 4 + kk) * HID + cx * 4];
                #pragma unroll
                for (int i = 0; i < 4; ++i) {
                    float xval = reinterpret_cast<const float*>(&xv[i])[kk];
                    acc[i][0] = fmaf(xval, w.x, acc[i][0]);
                    acc[i][1] = fmaf(xval, w.y, acc[i][1]);
                    acc[i][2] = fmaf(xval, w.z, acc[i][2]);
                    acc[i][3] = fmaf(xval, w.w, acc[i][3]);
                }
            }
        }
    }

    const float4 wpv = *(const float4*)&wp[cx * 4];
    const float4 wiv = *(const float4*)&attw[cx * 4];
    const float4 wjv = *(const float4*)&attw[HID + cx * 4];

    #pragma unroll
    for (int i = 0; i < 4; ++i) {
        const int node = node0 + i * 16 + ny;
        float h0v = fmaxf(acc[i][0], 0.f);
        float h1v = fmaxf(acc[i][1], 0.f);
        float h2v = fmaxf(acc[i][2], 0.f);
        float h3v = fmaxf(acc[i][3], 0.f);
        if (node < n) {
            float4 hv = make_float4(h0v, h1v, h2v, h3v);
            *(float4*)&h0[(size_t)node * HID + cx * 4] = hv;
        }
        float vd = h0v + h1v + h2v + h3v;
        float vw = h0v * wpv.x + h1v * wpv.y + h2v * wpv.z + h3v * wpv.w;
        float vi = h0v * wiv.x + h1v * wiv.y + h2v * wiv.z + h3v * wiv.w;
        float vj = h0v * wjv.x + h1v * wjv.y + h2v * wjv.z + h3v * wjv.w;
        #pragma unroll
        for (int m = 1; m < 16; m <<= 1) {
            vd += __shfl_xor(vd, m);
            vw += __shfl_xor(vw, m);
            vi += __shfl_xor(vi, m);
            vj += __shfl_xor(vj, m);
        }
        if (cx == 0 && node < n) {
            delta[node] = vd; hwp[node] = vw; ai[node] = vi; aj[node] = vj;
        }
    }
}

// ---------------- CSR scans (R14 exact) ----------------
__global__ __launch_bounds__(256) void k_scan1(
    const int* __restrict__ deg, int* __restrict__ rowptr,
    int* __restrict__ bsum, int n)
{
    __shared__ int sdata[256];
    const int t = threadIdx.x;
    const int i0 = blockIdx.x * 1024 + t * 4;
    int v[4];
    #pragma unroll
    for (int j = 0; j < 4; ++j) v[j] = (i0 + j < n) ? deg[i0 + j] : 0;
    int ts = v[0] + v[1] + v[2] + v[3];
    sdata[t] = ts;
    __syncthreads();
    for (int off = 1; off < 256; off <<= 1) {
        int add = (t >= off) ? sdata[t - off] : 0;
        __syncthreads();
        sdata[t] += add;
        __syncthreads();
    }
    int excl = sdata[t] - ts;
    int run = excl;
    #pragma unroll
    for (int j = 0; j < 4; ++j) {
        if (i0 + j < n) rowptr[i0 + j] = run;
        run += v[j];
    }
    if (t == 255) bsum[blockIdx.x] = sdata[255];
}

__global__ __launch_bounds__(128) void k_scan2(int* __restrict__ bsum, int B)
{
    __shared__ int sdata[128];
    const int t = threadIdx.x;
    int v = (t < B) ? bsum[t] : 0;
    sdata[t] = v;
    __syncthreads();
    for (int off = 1; off < 128; off <<= 1) {
        int add = (t >= off) ? sdata[t - off] : 0;
        __syncthreads();
        sdata[t] += add;
        __syncthreads();
    }
    if (t < B) bsum[t] = sdata[t] - v;
}

__global__ __launch_bounds__(256) void k_scan3(
    int* __restrict__ rowptr, int* __restrict__ cursor,
    const int* __restrict__ bsum, int n, int E)
{
    const int t = threadIdx.x;
    const int i0 = blockIdx.x * 1024 + t * 4;
    const int add = bsum[blockIdx.x];
    #pragma unroll
    for (int j = 0; j < 4; ++j) {
        int i = i0 + j;
        if (i < n) {
            int r = rowptr[i] + add;
            rowptr[i] = r;
            cursor[i] = r;
        }
    }
    if (blockIdx.x == 0 && t == 0) rowptr[n] = E;
}

// ---------------- Megakernel: place (bid%3!=0) || gemm64 layer-0 ----------
__global__ __launch_bounds__(256) void k_place_gemm(
    const int* __restrict__ src, const int* __restrict__ dst,
    int* __restrict__ cursor, int* __restrict__ csr_src, int E,
    const float* __restrict__ hin, const float* __restrict__ W,
    const float* __restrict__ b, float* __restrict__ hout, int n)
{
    __shared__ float xs[64 * 68];
    __shared__ float Ws[HID * HID];
    const int t = threadIdx.x;
    const int bid = blockIdx.x;

    if (bid % 3 != 0) {
        const int pid = (bid / 3) * 2 + (bid % 3 - 1);
        const int e = pid * 256 + t;
        if (e < E) {
            int slot = atomicAdd(cursor + dst[e], 1);
            csr_src[slot] = src[e];
        }
        return;
    }

    const int node0 = (bid / 3) * 64;

    #pragma unroll
    for (int p = 0; p < 4; ++p) {
        int c = t + p * 256;
        *(float4*)&Ws[c * 4] = *(const float4*)&W[c * 4];
    }
    #pragma unroll
    for (int p = 0; p < 4; ++p) {
        int c = t + p * 256;
        int row = c >> 4;
        int col = (c & 15) * 4;
        float4 v = make_float4(0.f, 0.f, 0.f, 0.f);
        if (node0 + row < n) v = *(const float4*)&hin[(size_t)(node0 + row) * HID + col];
        *(float4*)&xs[row * 68 + col] = v;
    }
    __syncthreads();

    const int cx = t & 15;
    const int ny = t >> 4;
    float acc[4][4];
    const float4 bv = *(const float4*)&b[cx * 4];
    #pragma unroll
    for (int i = 0; i < 4; ++i) {
        acc[i][0] = bv.x; acc[i][1] = bv.y; acc[i][2] = bv.z; acc[i][3] = bv.w;
    }

    #pragma unroll 4
    for (int k4 = 0; k4 < 16; ++k4) {
        float4 xv[4];
        #pragma unroll
        for (int i = 0; i < 4; ++i)
            xv[i] = *(const float4*)&xs[(i * 16 + ny) * 68 + k4 * 4];
        #pragma unroll
        for (int kk = 0; kk < 4; ++kk) {
            float4 w = *(const float4*)&Ws[(k4 * 4 + kk) * HID + cx * 4];
            #pragma unroll
            for (int i = 0; i < 4; ++i) {
                float xval = reinterpret_cast<const float*>(&xv[i])[kk];
                acc[i][0] = fmaf(xval, w.x, acc[i][0]);
                acc[i][1] = fmaf(xval, w.y, acc[i][1]);
                acc[i][2] = fmaf(xval, w.z, acc[i][2]);
                acc[i][3] = fmaf(xval, w.w, acc[i][3]);
            }
        }
    }

    #pragma unroll
    for (int i = 0; i < 4; ++i) {
        const int node = node0 + i * 16 + ny;
        if (node < n) {
            float4 hv = make_float4(acc[i][0], acc[i][1], acc[i][2], acc[i][3]);
            *(float4*)&hout[(size_t)node * HID + cx * 4] = hv;
        }
    }
}

// ---------------- neigh_pi (R14 exact) ----------------
__global__ __launch_bounds__(256) void k_neigh_pi(
    const int* __restrict__ rowptr, const int* __restrict__ csr_src,
    const float* __restrict__ delta, const float* __restrict__ hwp,
    float* __restrict__ pi, int n)
{
    int i = blockIdx.x * 256 + threadIdx.x;
    if (i >= n) return;
    int p0 = rowptr[i], p1 = rowptr[i + 1];
    float s = 0.f;
    for (int p = p0; p < p1; ++p) s += delta[csr_src[p]];
    float v = hwp[i] + s;
    pi[i] = 1.f / (1.f + expf(-v));
}

// ---------------- GEMM 64x64 (R14 exact, staged) ----------------
__global__ __launch_bounds__(256) void k_gemm64(
    const float* __restrict__ hin, const float* __restrict__ W,
    const float* __restrict__ b, float* __restrict__ hout, int n, int relu_in)
{
    __shared__ float xs[64 * 68];
    __shared__ float Ws[HID * HID];
    const int t = threadIdx.x;
    const int node0 = blockIdx.x * 64;

    #pragma unroll
    for (int p = 0; p < 4; ++p) {
        int c = t + p * 256;
        *(float4*)&Ws[c * 4] = *(const float4*)&W[c * 4];
    }
    #pragma unroll
    for (int p = 0; p < 4; ++p) {
        int c = t + p * 256;
        int row = c >> 4;
        int col = (c & 15) * 4;
        float4 v = make_float4(0.f, 0.f, 0.f, 0.f);
        if (node0 + row < n) v = *(const float4*)&hin[(size_t)(node0 + row) * HID + col];
        if (relu_in) {
            v.x = fmaxf(v.x, 0.f); v.y = fmaxf(v.y, 0.f);
            v.z = fmaxf(v.z, 0.f); v.w = fmaxf(v.w, 0.f);
        }
        *(float4*)&xs[row * 68 + col] = v;
    }
    __syncthreads();

    const int cx = t & 15;
    const int ny = t >> 4;
    float acc[4][4];
    const float4 bv = *(const float4*)&b[cx * 4];
    #pragma unroll
    for (int i = 0; i < 4; ++i) {
        acc[i][0] = bv.x; acc[i][1] = bv.y; acc[i][2] = bv.z; acc[i][3] = bv.w;
    }

    #pragma unroll 4
    for (int k4 = 0; k4 < 16; ++k4) {
        float4 xv[4];
        #pragma unroll
        for (int i = 0; i < 4; ++i)
            xv[i] = *(const float4*)&xs[(i * 16 + ny) * 68 + k4 * 4];
        #pragma unroll
        for (int kk = 0; kk < 4; ++kk) {
            float4 w = *(const float4*)&Ws[(k4 * 4 + kk) * HID + cx * 4];
            #pragma unroll
            for (int i = 0; i < 4; ++i) {
                float xval = reinterpret_cast<const float*>(&xv[i])[kk];
                acc[i][0] = fmaf(xval, w.x, acc[i][0]);
                acc[i][1] = fmaf(xval, w.y, acc[i][1]);
                acc[i][2] = fmaf(xval, w.z, acc[i][2]);
                acc[i][3] = fmaf(xval, w.w, acc[i][3]);
            }
        }
    }

    #pragma unroll
    for (int i = 0; i < 4; ++i) {
        const int node = node0 + i * 16 + ny;
        if (node < n) {
            float4 hv = make_float4(acc[i][0], acc[i][1], acc[i][2], acc[i][3]);
            *(float4*)&hout[(size_t)node * HID + cx * 4] = hv;
        }
    }
}

// ---------------- Gather (+ optional fused attention) ---------------------
// FUSE_ATT=1: compute alpha in-wave (exp of lrelu, tree-reduced denom),
// store normalized alpha for later gathers, then gather. FUSE_ATT=0: R14.
template<int FUSE_ATT>
__global__ __launch_bounds__(256) void k_gather(
    const int* __restrict__ rowptr, const int* __restrict__ csr_src,
    float* __restrict__ alpha_csr, const float* __restrict__ hl,
    float* __restrict__ out, int n,
    const float* __restrict__ ai, const float* __restrict__ aj,
    const float* __restrict__ pi, const float* __restrict__ attw,
    const float* __restrict__ attb)
{
    const int wave = threadIdx.x >> 6;
    const int lane = threadIdx.x & 63;
    const int g    = lane >> 4;
    const int q    = lane & 15;
    const int node = blockIdx.x * 4 + wave;
    if (node >= n) return;

    const int p0 = rowptr[node], p1 = rowptr[node + 1];

    float inv = 0.f;
    if (FUSE_ATT) {
        // pass 1: unnormalized exp-e per edge; tree-reduced denominator
        const float wpe = attw[2 * HID];
        const float ab  = attb[0];
        const float aid = ai[node];
        float den = 0.f;
        for (int base = p0; base < p1; base += 64) {
            int m = p1 - base; if (m > 64) m = 64;
            float ev = 0.f;
            if (lane < m) {
                int s = csr_src[base + lane];
                float v = aid + aj[s] + pi[s] * wpe + ab;
                v = v > 0.f ? v : 0.2f * v;
                ev = expf(v);
                alpha_csr[base + lane] = ev;   // unnormalized (fixed in pass 2)
            }
            float r = ev;
            #pragma unroll
            for (int m2 = 1; m2 < 64; m2 <<= 1) r += __shfl_xor(r, m2);
            den += r;
        }
        inv = 1.f / (den + 1e-16f);
    }

    float4 acc = make_float4(0.f, 0.f, 0.f, 0.f);

    for (int base = p0; base < p1; base += 64) {
        int m = p1 - base; if (m > 64) m = 64;
        float a_l = 0.f; int s_l = 0;
        if (lane < m) {
            a_l = alpha_csr[base + lane];
            if (FUSE_ATT) {
                a_l *= inv;
                alpha_csr[base + lane] = a_l;  // normalized for gathers 1/2
            }
            s_l = csr_src[base + lane];
        }
        int j = 0;
        for (; j + 16 <= m; j += 16) {       // 4 edges in flight per group
            float a0 = __shfl(a_l, j + g);      int s0 = __shfl(s_l, j + g);
            float a1 = __shfl(a_l, j + 4 + g);  int s1 = __shfl(s_l, j + 4 + g);
            float a2 = __shfl(a_l, j + 8 + g);  int s2 = __shfl(s_l, j + 8 + g);
            float a3 = __shfl(a_l, j + 12 + g); int s3 = __shfl(s_l, j + 12 + g);
            float4 v0 = *(const float4*)&hl[(size_t)s0 * HID + q * 4];
            float4 v1 = *(const float4*)&hl[(size_t)s1 * HID + q * 4];
            float4 v2 = *(const float4*)&hl[(size_t)s2 * HID + q * 4];
            float4 v3 = *(const float4*)&hl[(size_t)s3 * HID + q * 4];
            acc.x = fmaf(a0, v0.x, acc.x); acc.y = fmaf(a0, v0.y, acc.y);
            acc.z = fmaf(a0, v0.z, acc.z); acc.w = fmaf(a0, v0.w, acc.w);
            acc.x = fmaf(a1, v1.x, acc.x); acc.y = fmaf(a1, v1.y, acc.y);
            acc.z = fmaf(a1, v1.z, acc.z); acc.w = fmaf(a1, v1.w, acc.w);
            acc.x = fmaf(a2, v2.x, acc.x); acc.y = fmaf(a2, v2.y, acc.y);
            acc.z = fmaf(a2, v2.z, acc.z); acc.w = fmaf(a2, v2.w, acc.w);
            acc.x = fmaf(a3, v3.x, acc.x); acc.y = fmaf(a3, v3.y, acc.y);
            acc.z = fmaf(a3, v3.z, acc.z); acc.w = fmaf(a3, v3.w, acc.w);
        }
        for (; j + 8 <= m; j += 8) {         // 2 edges in flight per group
            float a0 = __shfl(a_l, j + g);     int s0 = __shfl(s_l, j + g);
            float a1 = __shfl(a_l, j + 4 + g); int s1 = __shfl(s_l, j + 4 + g);
            float4 v0 = *(const float4*)&hl[(size_t)s0 * HID + q * 4];
            float4 v1 = *(const float4*)&hl[(size_t)s1 * HID + q * 4];
            acc.x = fmaf(a0, v0.x, acc.x); acc.y = fmaf(a0, v0.y, acc.y);
            acc.z = fmaf(a0, v0.z, acc.z); acc.w = fmaf(a0, v0.w, acc.w);
            acc.x = fmaf(a1, v1.x, acc.x); acc.y = fmaf(a1, v1.y, acc.y);
            acc.z = fmaf(a1, v1.z, acc.z); acc.w = fmaf(a1, v1.w, acc.w);
        }
        for (; j < m; j += 4) {              // guarded tail
            const int e = j + g;
            float a = __shfl(a_l, e);
            int   s = __shfl(s_l, e);
            if (e < m) {
                float4 v = *(const float4*)&hl[(size_t)s * HID + q * 4];
                acc.x = fmaf(a, v.x, acc.x);
                acc.y = fmaf(a, v.y, acc.y);
                acc.z = fmaf(a, v.z, acc.z);
                acc.w = fmaf(a, v.w, acc.w);
            }
        }
    }
    #pragma unroll
    for (int m2 = 16; m2 <= 32; m2 <<= 1) {
        acc.x += __shfl_xor(acc.x, m2);
        acc.y += __shfl_xor(acc.y, m2);
        acc.z += __shfl_xor(acc.z, m2);
        acc.w += __shfl_xor(acc.w, m2);
    }
    if (g == 0)
        *(float4*)&out[(size_t)node * HID + q * 4] = acc;
}

// ---------------- Output GEMM 64x40 (R14 exact, staged) ----------------
__global__ __launch_bounds__(256) void k_out_gemm(
    const float* __restrict__ hin, const float* __restrict__ W,
    const float* __restrict__ b, float* __restrict__ out, int n)
{
    __shared__ float xs[128 * 68];
    __shared__ float Ws[HID * 40];
    const int t = threadIdx.x;
    const int node0 = blockIdx.x * 128;

    #pragma unroll
    for (int p = 0; p < 3; ++p) {
        int c = t + p * 256;
        if (c < 640) *(float4*)&Ws[c * 4] = *(const float4*)&W[c * 4];
    }
    #pragma unroll
    for (int p = 0; p < 8; ++p) {
        int c = t + p * 256;
        int row = c >> 4;
        int col = (c & 15) * 4;
        float4 v = make_float4(0.f, 0.f, 0.f, 0.f);
        if (node0 + row < n) v = *(const float4*)&hin[(size_t)(node0 + row) * HID + col];
        v.x = fmaxf(v.x, 0.f); v.y = fmaxf(v.y, 0.f);
        v.z = fmaxf(v.z, 0.f); v.w = fmaxf(v.w, 0.f);
        *(float4*)&xs[row * 68 + col] = v;
    }
    __syncthreads();

    const int cx = t & 7;
    const int ny = t >> 3;
    float acc[4][5];
    #pragma unroll
    for (int j = 0; j < 5; ++j) {
        float bj = b[5 * cx + j];
        #pragma unroll
        for (int i = 0; i < 4; ++i) acc[i][j] = bj;
    }

    #pragma unroll 4
    for (int k4 = 0; k4 < 16; ++k4) {
        float4 xv[4];
        #pragma unroll
        for (int i = 0; i < 4; ++i)
            xv[i] = *(const float4*)&xs[(i * 32 + ny) * 68 + k4 * 4];
        #pragma unroll
        for (int kk = 0; kk < 4; ++kk) {
            int k = k4 * 4 + kk;
            float w[5];
            #pragma unroll
            for (int j = 0; j < 5; ++j) w[j] = Ws[k * 40 + 5 * cx + j];
            #pragma unroll
            for (int i = 0; i < 4; ++i) {
                float xval = reinterpret_cast<const float*>(&xv[i])[kk];
                #pragma unroll
                for (int j = 0; j < 5; ++j)
                    acc[i][j] = fmaf(xval, w[j], acc[i][j]);
            }
        }
    }

    #pragma unroll
    for (int i = 0; i < 4; ++i) {
        const int node = node0 + i * 32 + ny;
        if (node < n) {
            #pragma unroll
            for (int j = 0; j < 5; ++j)
                out[(size_t)node * 40 + 5 * cx + j] = acc[i][j];
        }
    }
}

extern "C" void kernel_launch(void* const* d_in, const int* in_sizes, int n_in,
                              void* d_out, int out_size, void* d_ws, size_t ws_size,
                              hipStream_t stream) {
    const float* x    = (const float*)d_in[0];
    const int*   ei   = (const int*)d_in[1];
    const float* Win  = (const float*)d_in[2];
    const float* bin  = (const float*)d_in[3];
    const float* wp   = (const float*)d_in[4];
    const float* attw = (const float*)d_in[5];
    const float* attb = (const float*)d_in[6];
    const float* Wout = (const float*)d_in[7];
    const float* bout = (const float*)d_in[8];
    const float* W0   = (const float*)d_in[9];
    const float* b0   = (const float*)d_in[10];
    const float* W1   = (const float*)d_in[11];
    const float* b1   = (const float*)d_in[12];
    const float* W2   = (const float*)d_in[13];
    const float* b2   = (const float*)d_in[14];

    const int N = in_sizes[0] / INC;
    const int E = in_sizes[1] / 2;
    const int* src = ei;
    const int* dst = ei + E;
    float* out = (float*)d_out;

    char* ws = (char*)d_ws;
    size_t off = 0;
    auto alloc = [&](size_t bytes) -> void* {
        void* p = ws + off;
        off = (off + bytes + 255) & ~(size_t)255;
        return p;
    };
    float* A       = (float*)alloc((size_t)N * HID * 4);
    float* Bf      = (float*)alloc((size_t)N * HID * 4);
    float* C       = (float*)alloc((size_t)N * HID * 4);
    float* delta   = (float*)alloc((size_t)N * 4);
    float* hwp     = (float*)alloc((size_t)N * 4);
    float* ai      = (float*)alloc((size_t)N * 4);
    float* aj      = (float*)alloc((size_t)N * 4);
    float* pi      = (float*)alloc((size_t)N * 4);
    int*   deg     = (int*)alloc((size_t)N * 4);
    int*   rowptr  = (int*)alloc((size_t)(N + 1) * 4);
    int*   cursor  = (int*)alloc((size_t)N * 4);
    int*   bsum    = (int*)alloc(256 * 4);
    int*   csr_src = (int*)alloc((size_t)E * 4);
    float* alpha   = (float*)alloc((size_t)E * 4);

    const int tileBlocks64  = (N + 63) / 64;          // 1563
    const int tileBlocks128 = (N + 127) / 128;
    const int nodeBlocks256 = (N + 255) / 256;
    const int nodeBlocksW   = (N + 3) / 4;
    const int scanBlocks    = (N + 1023) / 1024;      // 98

    // 1 gemm block : 2 edge blocks; 2*1563=3126 >= ceil(E/256)=3125 (guarded)
    const int fusedBlocks = 3 * tileBlocks64;

    hipMemsetAsync(deg, 0, (size_t)N * 4, stream);

    // ---- in_gemm || degree count ----
    k_ingemm_deg<<<fusedBlocks, 256, 0, stream>>>(
        x, Win, bin, wp, attw, A, delta, hwp, ai, aj, N, dst, deg, E);

    // ---- rowptr scans ----
    k_scan1<<<scanBlocks, 256, 0, stream>>>(deg, rowptr, bsum, N);
    k_scan2<<<1, 128, 0, stream>>>(bsum, scanBlocks);
    k_scan3<<<scanBlocks, 256, 0, stream>>>(rowptr, cursor, bsum, N, E);

    // ---- place || gemm64 layer-0 (Bf = h0 @ W0 + b0) ----
    k_place_gemm<<<fusedBlocks, 256, 0, stream>>>(
        src, dst, cursor, csr_src, E, A, W0, b0, Bf, N);

    // ---- pi (needs csr + delta) ----
    k_neigh_pi<<<nodeBlocks256, 256, 0, stream>>>(rowptr, csr_src, delta, hwp, pi, N);

    // ---- layer 0: gather with fused attention (computes + stores alpha) ----
    k_gather<1><<<nodeBlocksW, 256, 0, stream>>>(rowptr, csr_src, alpha, Bf, C, N,
                                                 ai, aj, pi, attw, attb);

    k_gemm64<<<tileBlocks64, 256, 0, stream>>>(C, W1, b1, A, N, 1);
    k_gather<0><<<nodeBlocksW, 256, 0, stream>>>(rowptr, csr_src, alpha, A, Bf, N,
                                                 ai, aj, pi, attw, attb);

    k_gemm64<<<tileBlocks64, 256, 0, stream>>>(Bf, W2, b2, C, N, 1);
    k_gather<0><<<nodeBlocksW, 256, 0, stream>>>(rowptr, csr_src, alpha, C, A, N,
                                                 ai, aj, pi, attw, attb);

    k_out_gemm<<<tileBlocks128, 256, 0, stream>>>(A, Wout, bout, out, N);
}